// Round 5
// baseline (134.971 us; speedup 1.0000x reference)
//
#include <hip/hip_runtime.h>
#include <hip/hip_bf16.h>
#include <cstdint>
#include <cmath>

#define B_ 512
#define T_ 256
#define C_ 256
#define HS_ 64

typedef short bf16x8 __attribute__((ext_vector_type(8)));
typedef float f32x4 __attribute__((ext_vector_type(4)));

static __device__ __forceinline__ unsigned short f2bf(float f) {
    union { float f; unsigned int u; } v; v.f = f;
    unsigned int r = v.u + 0x7fffu + ((v.u >> 16) & 1u);
    return (unsigned short)(r >> 16);
}

// ---- Kernel 0: W -> pre-fragmented bf16 WTf.
// fb = (ws*4+f)*8 + kap ; WTf[fb*512 + l*8 + j] = W_ws[kap*32 + (l>>4)*8 + j][f*16 + (l&15)]
__global__ void wt_kernel(const float* __restrict__ Wq, const float* __restrict__ Wk,
                          const float* __restrict__ Wv, unsigned short* __restrict__ WTf) {
    int idx = blockIdx.x * 256 + threadIdx.x;     // 6144 total
    if (idx >= 96 * 64) return;
    int fb = idx >> 6;
    int l = idx & 63;
    int ws = fb >> 5;
    int rem = fb & 31;
    int f = rem >> 3;
    int kap = rem & 7;
    const float* W = (ws == 0) ? Wq : ((ws == 1) ? Wk : Wv);
    unsigned short o[8];
#pragma unroll
    for (int j = 0; j < 8; ++j) {
        int k = kap * 32 + (l >> 4) * 8 + j;
        int n = f * 16 + (l & 15);
        o[j] = f2bf(W[k * HS_ + n]);
    }
    *(ulonglong2*)(WTf + (size_t)idx * 8) = *(ulonglong2*)o;
}

// ---- Kernel 1: projection GEMM — LDS-free, barrier-free, register-direct.
// Block: 256 thr / 4 waves, 64 rows. Wave: 16 rows x 192 cols.
// A: fp32 direct global->VGPR in fragment order (convert in VALU).
// B: WTf fragments re-read per K-chunk (96 KB, L1/L2-hot).
__global__ __launch_bounds__(256, 3)
void proj_kernel(const float* __restrict__ x, const unsigned short* __restrict__ WTf,
                 unsigned short* __restrict__ Qb, unsigned short* __restrict__ Kb,
                 unsigned short* __restrict__ Vt) {
    const int tid = threadIdx.x;
    const int w = tid >> 6;
    const int l = tid & 63;
    const int ln = l & 15;
    const int lg = l >> 4;
    const int row = blockIdx.x * 64 + w * 16 + ln;       // this lane's x/output row
    const float* xrow = x + (size_t)row * C_ + lg * 8;

    f32x4 acc[3][4];
#pragma unroll
    for (int a = 0; a < 3; ++a)
#pragma unroll
        for (int f = 0; f < 4; ++f)
            acc[a][f] = (f32x4){0.f, 0.f, 0.f, 0.f};

#pragma unroll
    for (int h = 0; h < 2; ++h) {
        // load 4 K-chunks of A upfront (8 x dwordx4 per lane, 8 KB/wave in flight)
        float4 av[4][2];
#pragma unroll
        for (int k2 = 0; k2 < 4; ++k2) {
            av[k2][0] = *(const float4*)(xrow + (h * 4 + k2) * 32);
            av[k2][1] = *(const float4*)(xrow + (h * 4 + k2) * 32 + 4);
        }
#pragma unroll
        for (int k2 = 0; k2 < 4; ++k2) {
            const int kap = h * 4 + k2;
            bf16x8 a;
            a[0] = f2bf(av[k2][0].x); a[1] = f2bf(av[k2][0].y);
            a[2] = f2bf(av[k2][0].z); a[3] = f2bf(av[k2][0].w);
            a[4] = f2bf(av[k2][1].x); a[5] = f2bf(av[k2][1].y);
            a[6] = f2bf(av[k2][1].z); a[7] = f2bf(av[k2][1].w);
#pragma unroll
            for (int ws_ = 0; ws_ < 3; ++ws_)
#pragma unroll
                for (int f = 0; f < 4; ++f) {
                    bf16x8 bfr = *(const bf16x8*)(WTf
                        + ((size_t)((ws_ * 4 + f) * 8 + kap) * 64 + l) * 8);
                    acc[ws_][f] = __builtin_amdgcn_mfma_f32_16x16x32_bf16(
                        bfr, a, acc[ws_][f], 0, 0, 0);
                }
        }
    }

    // ---- epilogue: direct stores (lane = row `row`, cols f*16+lg*4..+3) ----
    // Q,K row-major: 8B ushort4 per (ws,f); lines assemble in L2.
#pragma unroll
    for (int ws_ = 0; ws_ < 2; ++ws_) {
        unsigned short* gdst = (ws_ == 0) ? Qb : Kb;
#pragma unroll
        for (int f = 0; f < 4; ++f) {
            ushort4 o;
            o.x = f2bf(acc[ws_][f][0]);
            o.y = f2bf(acc[ws_][f][1]);
            o.z = f2bf(acc[ws_][f][2]);
            o.w = f2bf(acc[ws_][f][3]);
            *(ushort4*)(gdst + (size_t)row * HS_ + f * 16 + lg * 4) = o;
        }
    }
    // V transposed: Vt[batch][col][trow]
    {
        unsigned short* gdst = Vt + (size_t)(row >> 8) * 16384 + (row & 255);
#pragma unroll
        for (int f = 0; f < 4; ++f)
#pragma unroll
            for (int i = 0; i < 4; ++i)
                gdst[(size_t)(f * 16 + lg * 4 + i) * 256] = f2bf(acc[2][f][i]);
    }
}

// ---- Kernel 2: flash-style causal attention (V pre-transposed) ----
__global__ __launch_bounds__(256)
void attn_kernel(const unsigned short* __restrict__ Qb, const unsigned short* __restrict__ Kb,
                 const unsigned short* __restrict__ Vt, float* __restrict__ out) {
    __shared__ unsigned short P_lds[4][16][40];

    const int w = threadIdx.x >> 6;
    const int l = threadIdx.x & 63;
    const int ln = l & 15;
    const int lg = l >> 4;
    const int b = blockIdx.x >> 2;
    const int qt = blockIdx.x & 3;
    const int q0 = qt * 64;
    const int r0 = q0 + w * 16;
    const size_t base = (size_t)b * T_ * HS_;
    const size_t vbase = (size_t)b * HS_ * T_;       // Vt: [64][256] per batch
    const float scale = 0.0625f;

    bf16x8 qa[2];
#pragma unroll
    for (int kk = 0; kk < 2; ++kk)
        qa[kk] = *(const bf16x8*)(Qb + base + (size_t)(r0 + ln) * HS_ + kk * 32 + lg * 8);

    float m[4], lsum[4];
    f32x4 o[4];
#pragma unroll
    for (int r = 0; r < 4; ++r) { m[r] = -INFINITY; lsum[r] = 0.f; }
#pragma unroll
    for (int f = 0; f < 4; ++f) o[f] = (f32x4){0.f, 0.f, 0.f, 0.f};

    const int nkt = qt * 2 + 2;
    for (int kt = 0; kt < nkt; ++kt) {
        const int n0 = kt * 32;

        f32x4 s[2];
#pragma unroll
        for (int h = 0; h < 2; ++h) {
            bf16x8 kb0 = *(const bf16x8*)(Kb + base + (size_t)(n0 + 16 * h + ln) * HS_ + lg * 8);
            bf16x8 kb1 = *(const bf16x8*)(Kb + base + (size_t)(n0 + 16 * h + ln) * HS_ + 32 + lg * 8);
            f32x4 z = (f32x4){0.f, 0.f, 0.f, 0.f};
            z = __builtin_amdgcn_mfma_f32_16x16x32_bf16(qa[0], kb0, z, 0, 0, 0);
            s[h] = __builtin_amdgcn_mfma_f32_16x16x32_bf16(qa[1], kb1, z, 0, 0, 0);
        }

        float sm[2][4];
#pragma unroll
        for (int r = 0; r < 4; ++r) {
            const int qrow = r0 + lg * 4 + r;
#pragma unroll
            for (int h = 0; h < 2; ++h) {
                float v = s[h][r] * scale;
                sm[h][r] = (qrow >= n0 + 16 * h + ln) ? v : -INFINITY;
            }
        }

        float fac[4], p[2][4];
#pragma unroll
        for (int r = 0; r < 4; ++r) {
            float tmax = fmaxf(sm[0][r], sm[1][r]);
#pragma unroll
            for (int mask = 1; mask < 16; mask <<= 1)
                tmax = fmaxf(tmax, __shfl_xor(tmax, mask, 64));
            float mn = fmaxf(m[r], tmax);
            fac[r] = __expf(m[r] - mn);
            p[0][r] = __expf(sm[0][r] - mn);
            p[1][r] = __expf(sm[1][r] - mn);
            float rs = p[0][r] + p[1][r];
#pragma unroll
            for (int mask = 1; mask < 16; mask <<= 1)
                rs += __shfl_xor(rs, mask, 64);
            lsum[r] = lsum[r] * fac[r] + rs;
            m[r] = mn;
        }
#pragma unroll
        for (int f = 0; f < 4; ++f)
#pragma unroll
            for (int r = 0; r < 4; ++r)
                o[f][r] *= fac[r];

#pragma unroll
        for (int h = 0; h < 2; ++h)
#pragma unroll
            for (int r = 0; r < 4; ++r)
                P_lds[w][lg * 4 + r][16 * h + ln] = f2bf(p[h][r]);

        bf16x8 pa = *(const bf16x8*)(&P_lds[w][ln][lg * 8]);

        // PV: V^T gives contiguous 16B B-fragments
#pragma unroll
        for (int f = 0; f < 4; ++f) {
            bf16x8 vb = *(const bf16x8*)(Vt + vbase + (size_t)(f * 16 + ln) * T_ + n0 + lg * 8);
            o[f] = __builtin_amdgcn_mfma_f32_16x16x32_bf16(pa, vb, o[f], 0, 0, 0);
        }
    }

#pragma unroll
    for (int f = 0; f < 4; ++f)
#pragma unroll
        for (int r = 0; r < 4; ++r) {
            int trow = r0 + lg * 4 + r;
            out[base + (size_t)trow * HS_ + 16 * f + ln] = o[f][r] / lsum[r];
        }
}

extern "C" void kernel_launch(void* const* d_in, const int* in_sizes, int n_in,
                              void* d_out, int out_size, void* d_ws, size_t ws_size,
                              hipStream_t stream) {
    const float* x  = (const float*)d_in[0];
    const float* Wq = (const float*)d_in[1];
    const float* Wk = (const float*)d_in[2];
    const float* Wv = (const float*)d_in[3];
    float* out = (float*)d_out;

    unsigned short* WTf = (unsigned short*)d_ws;                // 96 KB
    unsigned short* Qb = WTf + 96 * 64 * 8;
    unsigned short* Kb = Qb + (size_t)B_ * T_ * HS_;
    unsigned short* Vt = Kb + (size_t)B_ * T_ * HS_;

    wt_kernel<<<24, 256, 0, stream>>>(Wq, Wk, Wv, WTf);
    proj_kernel<<<(B_ * T_) / 64, 256, 0, stream>>>(x, WTf, Qb, Kb, Vt);
    attn_kernel<<<B_ * 4, 256, 0, stream>>>(Qb, Kb, Vt, out);
}